// Round 5
// baseline (234.982 us; speedup 1.0000x reference)
//
#include <hip/hip_runtime.h>
#include <stdint.h>

typedef int v4i __attribute__((ext_vector_type(4)));

// Problem dims
#define N_IMG 32
#define C_IN 256
#define H_IN 56
#define W_IN 56
#define C_OUT 256
#define H_OUT 28
#define W_OUT 28
#define H_PAD 58
#define W_PAD 58
#define SP_TOT (N_IMG*H_OUT*W_OUT)   // 25088

#define XPAD_BYTES ((size_t)N_IMG*H_PAD*W_PAD*C_IN)   // 27,557,888 (16B aligned)

// Activations stored in NATURAL channel order.

__device__ __forceinline__ void glds16(const int8_t* g, int8_t* l) {
    __builtin_amdgcn_global_load_lds(
        (const __attribute__((address_space(1))) void*)g,
        (__attribute__((address_space(3))) void*)l, 16, 0, 0);
}

// ---------------------------------------------------------------------------
// Kernel 1 (v3, UNCHANGED this round): quantize fp32 NCHW -> int8 NHWC,
// borders inline, weight repack fused as extra blockIdx.y slabs.
// R5 NOTE: launched 3x this round as an ATTRIBUTION PROBE (idempotent:
// pure function of x/w, fully overwrites xpad+wq -> output exact-match
// preserved). dur delta / 2 = quant cost + launch gap.
// ---------------------------------------------------------------------------
__global__ __launch_bounds__(256, 4) void quant_kernel(const float* __restrict__ x,
                                                       int8_t* __restrict__ xpad,
                                                       const float* __restrict__ w,
                                                       int8_t* __restrict__ wq) {
    __shared__ uint32_t ldsu[W_IN * 65];           // 14,560 B out-stage
    const int hp = blockIdx.x, n = blockIdx.y;
    const int t = threadIdx.x;

    if (n >= N_IMG) {
        // ---- fused weight repack: [co][ci][khw] -> wq[khw][co][ci] ----
        const int base = ((n - N_IMG) * H_PAD + hp) * 1024;
        #pragma unroll
        for (int i = 0; i < 4; ++i) {
            int idx = base + i * 256 + t;
            if (idx < 9 * C_OUT * C_IN) {
                int ci  = idx & 255;
                int co  = (idx >> 8) & 255;
                int khw = idx >> 16;
                float v = w[(size_t)(co * C_IN + ci) * 9 + khw];
                wq[idx] = (int8_t)(int)rintf(v);
            }
        }
        return;
    }

    int8_t* row = xpad + ((size_t)n * H_PAD + hp) * W_PAD * C_IN;

    if (hp == 0 || hp == H_PAD - 1) {
        // zero full padded row: 58*256 B = 928 x 16B
        #pragma unroll
        for (int i = 0; i < 4; ++i) {
            int idx = i * 256 + t;
            if (idx < 928) *(int4*)(row + idx * 16) = (int4){0, 0, 0, 0};
        }
        return;
    }
    const int h = hp - 1;
    const float* xrow = x + (size_t)n * (C_IN * H_IN * W_IN) + (size_t)h * W_IN;

    // zero border pixels w_p = 0 and w_p = 57 (32 x 16B), independent of loads
    if (t < 32) {
        int8_t* p = (t < 16) ? (row + t * 16)
                             : (row + (size_t)(W_PAD - 1) * C_IN + (t - 16) * 16);
        *(int4*)p = (int4){0, 0, 0, 0};
    }

    // ---- quantize + 4x4 shfl byte transpose -> ldsu (direct global reads) ----
    const int lane = t & 63, wv = t >> 6;
    const int j = lane >> 4, w4 = lane & 15;
    const int w4c = (w4 < 14) ? w4 : 13;           // clamp reads; store masked
    #pragma unroll
    for (int i16 = 0; i16 < 16; ++i16) {
        const int c4p = i16 * 4 + wv;              // output word index 0..63
        const float4 v = *(const float4*)(xrow + (size_t)(4 * c4p + j) * (H_IN * W_IN)
                                          + w4c * 4);
        float f[4] = {v.x, v.y, v.z, v.w};
        uint32_t u = 0;
        #pragma unroll
        for (int i = 0; i < 4; ++i) {
            float qv = rintf(f[i] * 20.0f);        // ~= x/0.05, see R4 notes
            qv = fminf(fmaxf(qv, -128.0f), 127.0f);
            u |= ((uint32_t)((int)qv & 255)) << (8 * i);  // byte i = w-offset i
        }
        // 4x4 byte transpose across lanes {j, same w4}  [verified R5]
        uint32_t p1 = __shfl_xor(u, 16);
        uint32_t tt = (j & 1) ? (((p1 >> 8) & 0x00FF00FFu) | (u & 0xFF00FF00u))
                              : ((u & 0x00FF00FFu) | ((p1 << 8) & 0xFF00FF00u));
        uint32_t p2 = __shfl_xor(tt, 32);
        uint32_t rr = (j & 2) ? ((p2 >> 16) | (tt & 0xFFFF0000u))
                              : ((tt & 0x0000FFFFu) | (p2 << 16));
        // lane now holds w = 4*w4 + j, channels 4*c4p .. 4*c4p+3 (natural order)
        if (w4 < 14) ldsu[(w4 * 4 + j) * 65 + c4p] = rr;
    }
    __syncthreads();

    // ---- write x_pad[n][hp][w+1][c], 256B/wave coalesced ----
    int8_t* op = row + C_IN;                       // w_p starts at 1
    #pragma unroll
    for (int it = 0; it < 14; ++it) {              // 56 w * 64 c4 = 3584
        int idx = it * 256 + t;
        int w_ = idx >> 6, c4 = idx & 63;
        *(uint32_t*)(op + (size_t)w_ * C_IN + c4 * 4) = ldsu[w_ * 65 + c4];
    }
}

// ---------------------------------------------------------------------------
// Kernel 3 (v5, UNCHANGED -- the R4 winner): implicit-GEMM conv.
// Wave tile 64co x 64sp (acc[4][4]), block 128co x 128sp, grid 392.
// 36 stages BK=64, 3 bufs 48KB, counted-vmcnt depth-2, one barrier/stage.
// C/D: col(sp) = s, row(co) = q*4 + reg   [verified mapping]
// ---------------------------------------------------------------------------
__global__ __launch_bounds__(256, 3) void conv_kernel(const int8_t* __restrict__ xpad,
                                                      const int8_t* __restrict__ wq,
                                                      float* __restrict__ out) {
    __shared__ __align__(16) int8_t lds[49152];  // 3 bufs x (W 8KB + Act 8KB)
    const int t = threadIdx.x;
    const int wave = t >> 6, lane = t & 63;
    const int q = lane >> 4, s = lane & 15;

    // XCD-chunked bijective swizzle (392 = 8*49), co-inner pairing
    const int wg = blockIdx.x;                    // 0..391
    const int lg = (wg & 7) * 49 + (wg >> 3);     // logical work index
    const int co_blk = (lg & 1) * 128;
    const int sp_blk = (lg >> 1) * 128;

    // ---- staging decode: thread t -> (row = t>>2, chunk cl = t&3) ----
    const int srow = t >> 2;                      // 0..63
    const int scl  = t & 3;
    const int sq   = scl ^ ((srow >> 1) & 3);     // pre-swizzled source chunk
    const int8_t* gw0 = wq + (size_t)(co_blk + srow) * 256 + sq * 16;
    const int8_t* gw1 = wq + (size_t)(co_blk + 64 + srow) * 256 + sq * 16;
    const int8_t* ga0;
    const int8_t* ga1;
    {
        int spA = sp_blk + srow;
        int nA  = spA / (H_OUT * W_OUT);
        int rmA = spA - nA * (H_OUT * W_OUT);
        int hoA = rmA / W_OUT;
        int woA = rmA - hoA * W_OUT;
        ga0 = xpad + ((size_t)(nA * H_PAD + hoA * 2) * W_PAD + woA * 2) * C_IN + sq * 16;
        int spB = sp_blk + 64 + srow;
        int nB  = spB / (H_OUT * W_OUT);
        int rmB = spB - nB * (H_OUT * W_OUT);
        int hoB = rmB / W_OUT;
        int woB = rmB - hoB * W_OUT;
        ga1 = xpad + ((size_t)(nB * H_PAD + hoB * 2) * W_PAD + woB * 2) * C_IN + sq * 16;
    }

    // ---- output mapping: wave tile 64co x 64sp (2x2 wave grid) ----
    const int cw = (wave >> 1) * 64;
    const int sw = (wave & 1) * 64;
    int out_base[4];
    #pragma unroll
    for (int jj = 0; jj < 4; ++jj) {
        int sp = sp_blk + sw + jj * 16 + s;
        int n  = sp / (H_OUT * W_OUT);
        int rm = sp - n * (H_OUT * W_OUT);
        int ho = rm / W_OUT;
        int wo = rm - ho * W_OUT;
        out_base[jj] = n * (C_OUT * H_OUT * W_OUT) + ho * W_OUT + wo;
    }

    v4i acc[4][4];
    #pragma unroll
    for (int i = 0; i < 4; ++i)
        #pragma unroll
        for (int jj = 0; jj < 4; ++jj)
            acc[i][jj] = (v4i){0, 0, 0, 0};

    // stage hk (tap = hk>>2, k-slice sl = hk&3) into buffer lb
    auto stage = [&](int hk, int8_t* lb) {
        const int tap = hk >> 2, sl = hk & 3;
        const int wo_ = tap * (C_OUT * C_IN) + sl * 64;
        const int ao_ = ((tap / 3) * W_PAD + (tap % 3)) * C_IN + sl * 64;
        glds16(gw0 + wo_, lb + t * 16);               // W rows 0..63
        glds16(gw1 + wo_, lb + 4096 + t * 16);        // W rows 64..127
        glds16(ga0 + ao_, lb + 8192 + t * 16);        // Act rows 0..63
        glds16(ga1 + ao_, lb + 12288 + t * 16);       // Act rows 64..127
    };

    // compute one stage (K=64) from buffer lb: 8 ds_read_b128, 16 MFMA
    auto compute = [&](const int8_t* lb) {
        const int stoff = (q ^ ((s >> 1) & 3)) * 16;  // swizzled chunk
        v4i a[4], b[4];
        #pragma unroll
        for (int i = 0; i < 4; ++i)
            a[i] = *(const v4i*)(lb + (cw + i * 16 + s) * 64 + stoff);
        #pragma unroll
        for (int jj = 0; jj < 4; ++jj)
            b[jj] = *(const v4i*)(lb + 8192 + (sw + jj * 16 + s) * 64 + stoff);
        #pragma unroll
        for (int i = 0; i < 4; ++i)
            #pragma unroll
            for (int jj = 0; jj < 4; ++jj)
                acc[i][jj] = __builtin_amdgcn_mfma_i32_16x16x64_i8(
                    a[i], b[jj], acc[i][jj], 0, 0, 0);
    };

    // ---- K loop: 36 stages, depth-2 counted-vmcnt, ONE barrier/stage ----
    stage(0, lds);
    stage(1, lds + 16384);
    #pragma unroll
    for (int hk = 0; hk < 36; ++hk) {
        // wait for stage hk's 4 loads (outstanding: hk, hk+1 -> 8 loads)
        if (hk < 35)
            asm volatile("s_waitcnt vmcnt(4)\n\ts_barrier" ::: "memory");
        else
            asm volatile("s_waitcnt vmcnt(0)\n\ts_barrier" ::: "memory");
        // barrier proves all waves retired buf((hk-1)%3) reads -> refill it
        if (hk + 2 < 36) stage(hk + 2, lds + ((hk + 2) % 3) * 16384);
        compute(lds + (hk % 3) * 16384);
    }

    // ---- epilogue: coalesced dword stores (lanes 0-15 = consecutive sp) ----
    #pragma unroll
    for (int jj = 0; jj < 4; ++jj) {
        #pragma unroll
        for (int i = 0; i < 4; ++i) {
            const int co0 = co_blk + cw + i * 16 + q * 4;
            #pragma unroll
            for (int r = 0; r < 4; ++r) {
                out[(size_t)out_base[jj] + (size_t)(co0 + r) * (H_OUT * W_OUT)] =
                    (float)acc[i][jj][r] * 0.0005f;
            }
        }
    }
}

// ---------------------------------------------------------------------------
// R5 ATTRIBUTION PROBE: quant launched 3x (idempotent), conv 1x.
// dur_us ~= best + 2*(Q + gap)  ->  solves quant's true per-launch cost Q.
// Decision tree: Q >= 30 -> attack quant read pattern next; Q <= 25 ->
// conv/gap residual or roofline.
// ---------------------------------------------------------------------------
extern "C" void kernel_launch(void* const* d_in, const int* in_sizes, int n_in,
                              void* d_out, int out_size, void* d_ws, size_t ws_size,
                              hipStream_t stream) {
    const float* x = (const float*)d_in[0];
    const float* w = (const float*)d_in[1];
    float* out = (float*)d_out;
    int8_t* xpad = (int8_t*)d_ws;
    int8_t* wqb  = xpad + XPAD_BYTES;

    quant_kernel<<<dim3(H_PAD, N_IMG + 10), 256, 0, stream>>>(x, xpad, w, wqb);
    quant_kernel<<<dim3(H_PAD, N_IMG + 10), 256, 0, stream>>>(x, xpad, w, wqb);
    quant_kernel<<<dim3(H_PAD, N_IMG + 10), 256, 0, stream>>>(x, xpad, w, wqb);
    conv_kernel<<<dim3(392), 256, 0, stream>>>(xpad, wqb, out);
}

// Round 6
// 227.753 us; speedup vs baseline: 1.0317x; 1.0317x over previous
//
#include <hip/hip_runtime.h>
#include <stdint.h>

typedef int v4i __attribute__((ext_vector_type(4)));

// Problem dims
#define N_IMG 32
#define C_IN 256
#define H_IN 56
#define W_IN 56
#define C_OUT 256
#define H_OUT 28
#define W_OUT 28
#define H_PAD 58
#define W_PAD 58
#define SP_TOT (N_IMG*H_OUT*W_OUT)   // 25088

#define XPAD_BYTES ((size_t)N_IMG*H_PAD*W_PAD*C_IN)   // 27,557,888 (16B aligned)

// Activations stored in NATURAL channel order.

__device__ __forceinline__ void glds16(const int8_t* g, int8_t* l) {
    __builtin_amdgcn_global_load_lds(
        (const __attribute__((address_space(1))) void*)g,
        (__attribute__((address_space(3))) void*)l, 16, 0, 0);
}

// ---------------------------------------------------------------------------
// Kernel 1 (v3, UNCHANGED): quantize fp32 NCHW -> int8 NHWC, borders inline,
// weight repack fused as extra blockIdx.y slabs.
// R5 probe result: Q + gap = 25.0 us (quant at ~88% of its 20.7 us floor).
// ---------------------------------------------------------------------------
__global__ __launch_bounds__(256, 4) void quant_kernel(const float* __restrict__ x,
                                                       int8_t* __restrict__ xpad,
                                                       const float* __restrict__ w,
                                                       int8_t* __restrict__ wq) {
    __shared__ uint32_t ldsu[W_IN * 65];           // 14,560 B out-stage
    const int hp = blockIdx.x, n = blockIdx.y;
    const int t = threadIdx.x;

    if (n >= N_IMG) {
        // ---- fused weight repack: [co][ci][khw] -> wq[khw][co][ci] ----
        const int base = ((n - N_IMG) * H_PAD + hp) * 1024;
        #pragma unroll
        for (int i = 0; i < 4; ++i) {
            int idx = base + i * 256 + t;
            if (idx < 9 * C_OUT * C_IN) {
                int ci  = idx & 255;
                int co  = (idx >> 8) & 255;
                int khw = idx >> 16;
                float v = w[(size_t)(co * C_IN + ci) * 9 + khw];
                wq[idx] = (int8_t)(int)rintf(v);
            }
        }
        return;
    }

    int8_t* row = xpad + ((size_t)n * H_PAD + hp) * W_PAD * C_IN;

    if (hp == 0 || hp == H_PAD - 1) {
        // zero full padded row: 58*256 B = 928 x 16B
        #pragma unroll
        for (int i = 0; i < 4; ++i) {
            int idx = i * 256 + t;
            if (idx < 928) *(int4*)(row + idx * 16) = (int4){0, 0, 0, 0};
        }
        return;
    }
    const int h = hp - 1;
    const float* xrow = x + (size_t)n * (C_IN * H_IN * W_IN) + (size_t)h * W_IN;

    // zero border pixels w_p = 0 and w_p = 57 (32 x 16B), independent of loads
    if (t < 32) {
        int8_t* p = (t < 16) ? (row + t * 16)
                             : (row + (size_t)(W_PAD - 1) * C_IN + (t - 16) * 16);
        *(int4*)p = (int4){0, 0, 0, 0};
    }

    // ---- quantize + 4x4 shfl byte transpose -> ldsu (direct global reads) ----
    const int lane = t & 63, wv = t >> 6;
    const int j = lane >> 4, w4 = lane & 15;
    const int w4c = (w4 < 14) ? w4 : 13;           // clamp reads; store masked
    #pragma unroll
    for (int i16 = 0; i16 < 16; ++i16) {
        const int c4p = i16 * 4 + wv;              // output word index 0..63
        const float4 v = *(const float4*)(xrow + (size_t)(4 * c4p + j) * (H_IN * W_IN)
                                          + w4c * 4);
        float f[4] = {v.x, v.y, v.z, v.w};
        uint32_t u = 0;
        #pragma unroll
        for (int i = 0; i < 4; ++i) {
            float qv = rintf(f[i] * 20.0f);        // ~= x/0.05, see R4 notes
            qv = fminf(fmaxf(qv, -128.0f), 127.0f);
            u |= ((uint32_t)((int)qv & 255)) << (8 * i);  // byte i = w-offset i
        }
        // 4x4 byte transpose across lanes {j, same w4}  [verified R5]
        uint32_t p1 = __shfl_xor(u, 16);
        uint32_t tt = (j & 1) ? (((p1 >> 8) & 0x00FF00FFu) | (u & 0xFF00FF00u))
                              : ((u & 0x00FF00FFu) | ((p1 << 8) & 0xFF00FF00u));
        uint32_t p2 = __shfl_xor(tt, 32);
        uint32_t rr = (j & 2) ? ((p2 >> 16) | (tt & 0xFFFF0000u))
                              : ((tt & 0x0000FFFFu) | (p2 << 16));
        // lane now holds w = 4*w4 + j, channels 4*c4p .. 4*c4p+3 (natural order)
        if (w4 < 14) ldsu[(w4 * 4 + j) * 65 + c4p] = rr;
    }
    __syncthreads();

    // ---- write x_pad[n][hp][w+1][c], 256B/wave coalesced ----
    int8_t* op = row + C_IN;                       // w_p starts at 1
    #pragma unroll
    for (int it = 0; it < 14; ++it) {              // 56 w * 64 c4 = 3584
        int idx = it * 256 + t;
        int w_ = idx >> 6, c4 = idx & 63;
        *(uint32_t*)(op + (size_t)w_ * C_IN + c4 * 4) = ldsu[w_ * 65 + c4];
    }
}

// ---------------------------------------------------------------------------
// Kernel 3 (v5, UNCHANGED -- the R4 winner): implicit-GEMM conv.
// Wave tile 64co x 64sp (acc[4][4]), block 128co x 128sp, grid 392.
// 36 stages BK=64, 3 bufs 48KB, counted-vmcnt depth-2, one barrier/stage.
// R6 NOTE: launched 3x as ATTRIBUTION PROBE (idempotent: reads xpad/wq,
// deterministically overwrites out -> exactness preserved).
// C/D: col(sp) = s, row(co) = q*4 + reg   [verified mapping]
// ---------------------------------------------------------------------------
__global__ __launch_bounds__(256, 3) void conv_kernel(const int8_t* __restrict__ xpad,
                                                      const int8_t* __restrict__ wq,
                                                      float* __restrict__ out) {
    __shared__ __align__(16) int8_t lds[49152];  // 3 bufs x (W 8KB + Act 8KB)
    const int t = threadIdx.x;
    const int wave = t >> 6, lane = t & 63;
    const int q = lane >> 4, s = lane & 15;

    // XCD-chunked bijective swizzle (392 = 8*49), co-inner pairing
    const int wg = blockIdx.x;                    // 0..391
    const int lg = (wg & 7) * 49 + (wg >> 3);     // logical work index
    const int co_blk = (lg & 1) * 128;
    const int sp_blk = (lg >> 1) * 128;

    // ---- staging decode: thread t -> (row = t>>2, chunk cl = t&3) ----
    const int srow = t >> 2;                      // 0..63
    const int scl  = t & 3;
    const int sq   = scl ^ ((srow >> 1) & 3);     // pre-swizzled source chunk
    const int8_t* gw0 = wq + (size_t)(co_blk + srow) * 256 + sq * 16;
    const int8_t* gw1 = wq + (size_t)(co_blk + 64 + srow) * 256 + sq * 16;
    const int8_t* ga0;
    const int8_t* ga1;
    {
        int spA = sp_blk + srow;
        int nA  = spA / (H_OUT * W_OUT);
        int rmA = spA - nA * (H_OUT * W_OUT);
        int hoA = rmA / W_OUT;
        int woA = rmA - hoA * W_OUT;
        ga0 = xpad + ((size_t)(nA * H_PAD + hoA * 2) * W_PAD + woA * 2) * C_IN + sq * 16;
        int spB = sp_blk + 64 + srow;
        int nB  = spB / (H_OUT * W_OUT);
        int rmB = spB - nB * (H_OUT * W_OUT);
        int hoB = rmB / W_OUT;
        int woB = rmB - hoB * W_OUT;
        ga1 = xpad + ((size_t)(nB * H_PAD + hoB * 2) * W_PAD + woB * 2) * C_IN + sq * 16;
    }

    // ---- output mapping: wave tile 64co x 64sp (2x2 wave grid) ----
    const int cw = (wave >> 1) * 64;
    const int sw = (wave & 1) * 64;
    int out_base[4];
    #pragma unroll
    for (int jj = 0; jj < 4; ++jj) {
        int sp = sp_blk + sw + jj * 16 + s;
        int n  = sp / (H_OUT * W_OUT);
        int rm = sp - n * (H_OUT * W_OUT);
        int ho = rm / W_OUT;
        int wo = rm - ho * W_OUT;
        out_base[jj] = n * (C_OUT * H_OUT * W_OUT) + ho * W_OUT + wo;
    }

    v4i acc[4][4];
    #pragma unroll
    for (int i = 0; i < 4; ++i)
        #pragma unroll
        for (int jj = 0; jj < 4; ++jj)
            acc[i][jj] = (v4i){0, 0, 0, 0};

    // stage hk (tap = hk>>2, k-slice sl = hk&3) into buffer lb
    auto stage = [&](int hk, int8_t* lb) {
        const int tap = hk >> 2, sl = hk & 3;
        const int wo_ = tap * (C_OUT * C_IN) + sl * 64;
        const int ao_ = ((tap / 3) * W_PAD + (tap % 3)) * C_IN + sl * 64;
        glds16(gw0 + wo_, lb + t * 16);               // W rows 0..63
        glds16(gw1 + wo_, lb + 4096 + t * 16);        // W rows 64..127
        glds16(ga0 + ao_, lb + 8192 + t * 16);        // Act rows 0..63
        glds16(ga1 + ao_, lb + 12288 + t * 16);       // Act rows 64..127
    };

    // compute one stage (K=64) from buffer lb: 8 ds_read_b128, 16 MFMA
    auto compute = [&](const int8_t* lb) {
        const int stoff = (q ^ ((s >> 1) & 3)) * 16;  // swizzled chunk
        v4i a[4], b[4];
        #pragma unroll
        for (int i = 0; i < 4; ++i)
            a[i] = *(const v4i*)(lb + (cw + i * 16 + s) * 64 + stoff);
        #pragma unroll
        for (int jj = 0; jj < 4; ++jj)
            b[jj] = *(const v4i*)(lb + 8192 + (sw + jj * 16 + s) * 64 + stoff);
        #pragma unroll
        for (int i = 0; i < 4; ++i)
            #pragma unroll
            for (int jj = 0; jj < 4; ++jj)
                acc[i][jj] = __builtin_amdgcn_mfma_i32_16x16x64_i8(
                    a[i], b[jj], acc[i][jj], 0, 0, 0);
    };

    // ---- K loop: 36 stages, depth-2 counted-vmcnt, ONE barrier/stage ----
    stage(0, lds);
    stage(1, lds + 16384);
    #pragma unroll
    for (int hk = 0; hk < 36; ++hk) {
        // wait for stage hk's 4 loads (outstanding: hk, hk+1 -> 8 loads)
        if (hk < 35)
            asm volatile("s_waitcnt vmcnt(4)\n\ts_barrier" ::: "memory");
        else
            asm volatile("s_waitcnt vmcnt(0)\n\ts_barrier" ::: "memory");
        // barrier proves all waves retired buf((hk-1)%3) reads -> refill it
        if (hk + 2 < 36) stage(hk + 2, lds + ((hk + 2) % 3) * 16384);
        compute(lds + (hk % 3) * 16384);
    }

    // ---- epilogue: coalesced dword stores (lanes 0-15 = consecutive sp) ----
    #pragma unroll
    for (int jj = 0; jj < 4; ++jj) {
        #pragma unroll
        for (int i = 0; i < 4; ++i) {
            const int co0 = co_blk + cw + i * 16 + q * 4;
            #pragma unroll
            for (int r = 0; r < 4; ++r) {
                out[(size_t)out_base[jj] + (size_t)(co0 + r) * (H_OUT * W_OUT)] =
                    (float)acc[i][jj][r] * 0.0005f;
            }
        }
    }
}

// ---------------------------------------------------------------------------
// R6 ATTRIBUTION PROBE: quant 1x, conv 3x (idempotent).
// dur_us ~= 184.9 + 2*(C + gap)  ->  solves conv's true per-launch cost C.
// Decision tree (pre-committed): C >= 28 -> conv has >=2x-floor headroom,
// attack conv (setprio / BK=128 stages / LDS-read reduction). C <= 24 ->
// kernels within ~6us of combined floor -> declare roofline.
// ---------------------------------------------------------------------------
extern "C" void kernel_launch(void* const* d_in, const int* in_sizes, int n_in,
                              void* d_out, int out_size, void* d_ws, size_t ws_size,
                              hipStream_t stream) {
    const float* x = (const float*)d_in[0];
    const float* w = (const float*)d_in[1];
    float* out = (float*)d_out;
    int8_t* xpad = (int8_t*)d_ws;
    int8_t* wqb  = xpad + XPAD_BYTES;

    quant_kernel<<<dim3(H_PAD, N_IMG + 10), 256, 0, stream>>>(x, xpad, w, wqb);
    conv_kernel<<<dim3(392), 256, 0, stream>>>(xpad, wqb, out);
    conv_kernel<<<dim3(392), 256, 0, stream>>>(xpad, wqb, out);
    conv_kernel<<<dim3(392), 256, 0, stream>>>(xpad, wqb, out);
}

// Round 7
// 184.389 us; speedup vs baseline: 1.2744x; 1.2352x over previous
//
#include <hip/hip_runtime.h>
#include <stdint.h>

typedef int v4i __attribute__((ext_vector_type(4)));

// Problem dims
#define N_IMG 32
#define C_IN 256
#define H_IN 56
#define W_IN 56
#define C_OUT 256
#define H_OUT 28
#define W_OUT 28
#define H_PAD 58
#define W_PAD 58
#define SP_TOT (N_IMG*H_OUT*W_OUT)   // 25088

#define XPAD_BYTES ((size_t)N_IMG*H_PAD*W_PAD*C_IN)   // 27,557,888 (16B aligned)

// Activations stored in NATURAL channel order.

__device__ __forceinline__ void glds16(const int8_t* g, int8_t* l) {
    __builtin_amdgcn_global_load_lds(
        (const __attribute__((address_space(1))) void*)g,
        (__attribute__((address_space(3))) void*)l, 16, 0, 0);
}

// ---------------------------------------------------------------------------
// Kernel 1 (v3): quantize fp32 NCHW -> int8 NHWC, borders inline, weight
// repack fused as extra blockIdx.y slabs.
// Measured (R5 probe): Q + gap = 25.0 us vs 20.7 us BW floor (~88%).
// ---------------------------------------------------------------------------
__global__ __launch_bounds__(256, 4) void quant_kernel(const float* __restrict__ x,
                                                       int8_t* __restrict__ xpad,
                                                       const float* __restrict__ w,
                                                       int8_t* __restrict__ wq) {
    __shared__ uint32_t ldsu[W_IN * 65];           // 14,560 B out-stage
    const int hp = blockIdx.x, n = blockIdx.y;
    const int t = threadIdx.x;

    if (n >= N_IMG) {
        // ---- fused weight repack: [co][ci][khw] -> wq[khw][co][ci] ----
        const int base = ((n - N_IMG) * H_PAD + hp) * 1024;
        #pragma unroll
        for (int i = 0; i < 4; ++i) {
            int idx = base + i * 256 + t;
            if (idx < 9 * C_OUT * C_IN) {
                int ci  = idx & 255;
                int co  = (idx >> 8) & 255;
                int khw = idx >> 16;
                float v = w[(size_t)(co * C_IN + ci) * 9 + khw];
                wq[idx] = (int8_t)(int)rintf(v);
            }
        }
        return;
    }

    int8_t* row = xpad + ((size_t)n * H_PAD + hp) * W_PAD * C_IN;

    if (hp == 0 || hp == H_PAD - 1) {
        // zero full padded row: 58*256 B = 928 x 16B
        #pragma unroll
        for (int i = 0; i < 4; ++i) {
            int idx = i * 256 + t;
            if (idx < 928) *(int4*)(row + idx * 16) = (int4){0, 0, 0, 0};
        }
        return;
    }
    const int h = hp - 1;
    const float* xrow = x + (size_t)n * (C_IN * H_IN * W_IN) + (size_t)h * W_IN;

    // zero border pixels w_p = 0 and w_p = 57 (32 x 16B), independent of loads
    if (t < 32) {
        int8_t* p = (t < 16) ? (row + t * 16)
                             : (row + (size_t)(W_PAD - 1) * C_IN + (t - 16) * 16);
        *(int4*)p = (int4){0, 0, 0, 0};
    }

    // ---- quantize + 4x4 shfl byte transpose -> ldsu (direct global reads) ----
    const int lane = t & 63, wv = t >> 6;
    const int j = lane >> 4, w4 = lane & 15;
    const int w4c = (w4 < 14) ? w4 : 13;           // clamp reads; store masked
    #pragma unroll
    for (int i16 = 0; i16 < 16; ++i16) {
        const int c4p = i16 * 4 + wv;              // output word index 0..63
        const float4 v = *(const float4*)(xrow + (size_t)(4 * c4p + j) * (H_IN * W_IN)
                                          + w4c * 4);
        float f[4] = {v.x, v.y, v.z, v.w};
        uint32_t u = 0;
        #pragma unroll
        for (int i = 0; i < 4; ++i) {
            float qv = rintf(f[i] * 20.0f);        // ~= x/0.05, see R4 notes
            qv = fminf(fmaxf(qv, -128.0f), 127.0f);
            u |= ((uint32_t)((int)qv & 255)) << (8 * i);  // byte i = w-offset i
        }
        // 4x4 byte transpose across lanes {j, same w4}  [verified R5]
        uint32_t p1 = __shfl_xor(u, 16);
        uint32_t tt = (j & 1) ? (((p1 >> 8) & 0x00FF00FFu) | (u & 0xFF00FF00u))
                              : ((u & 0x00FF00FFu) | ((p1 << 8) & 0xFF00FF00u));
        uint32_t p2 = __shfl_xor(tt, 32);
        uint32_t rr = (j & 2) ? ((p2 >> 16) | (tt & 0xFFFF0000u))
                              : ((tt & 0x0000FFFFu) | (p2 << 16));
        // lane now holds w = 4*w4 + j, channels 4*c4p .. 4*c4p+3 (natural order)
        if (w4 < 14) ldsu[(w4 * 4 + j) * 65 + c4p] = rr;
    }
    __syncthreads();

    // ---- write x_pad[n][hp][w+1][c], 256B/wave coalesced ----
    int8_t* op = row + C_IN;                       // w_p starts at 1
    #pragma unroll
    for (int it = 0; it < 14; ++it) {              // 56 w * 64 c4 = 3584
        int idx = it * 256 + t;
        int w_ = idx >> 6, c4 = idx & 63;
        *(uint32_t*)(op + (size_t)w_ * C_IN + c4 * 4) = ldsu[w_ * 65 + c4];
    }
}

// ---------------------------------------------------------------------------
// Kernel 3 (v5 -- the R4 winner, frozen): implicit-GEMM conv.
// Wave tile 64co x 64sp (acc[4][4], 65.5 int8-ops/LDS-byte), block
// 128co x 128sp, grid 392 (all resident). 36 stages BK=64, 3 bufs 48KB,
// counted-vmcnt depth-2, one barrier/stage.
// Measured (R6 probe): C + gap = 21.4 us vs ~9-10 us overlap-perfect floor;
// resisted 4 structural variants -- the register-tile change was the lever.
// C/D: col(sp) = s, row(co) = q*4 + reg   [verified mapping]
// ---------------------------------------------------------------------------
__global__ __launch_bounds__(256, 3) void conv_kernel(const int8_t* __restrict__ xpad,
                                                      const int8_t* __restrict__ wq,
                                                      float* __restrict__ out) {
    __shared__ __align__(16) int8_t lds[49152];  // 3 bufs x (W 8KB + Act 8KB)
    const int t = threadIdx.x;
    const int wave = t >> 6, lane = t & 63;
    const int q = lane >> 4, s = lane & 15;

    // XCD-chunked bijective swizzle (392 = 8*49), co-inner pairing
    const int wg = blockIdx.x;                    // 0..391
    const int lg = (wg & 7) * 49 + (wg >> 3);     // logical work index
    const int co_blk = (lg & 1) * 128;
    const int sp_blk = (lg >> 1) * 128;

    // ---- staging decode: thread t -> (row = t>>2, chunk cl = t&3) ----
    const int srow = t >> 2;                      // 0..63
    const int scl  = t & 3;
    const int sq   = scl ^ ((srow >> 1) & 3);     // pre-swizzled source chunk
    const int8_t* gw0 = wq + (size_t)(co_blk + srow) * 256 + sq * 16;
    const int8_t* gw1 = wq + (size_t)(co_blk + 64 + srow) * 256 + sq * 16;
    const int8_t* ga0;
    const int8_t* ga1;
    {
        int spA = sp_blk + srow;
        int nA  = spA / (H_OUT * W_OUT);
        int rmA = spA - nA * (H_OUT * W_OUT);
        int hoA = rmA / W_OUT;
        int woA = rmA - hoA * W_OUT;
        ga0 = xpad + ((size_t)(nA * H_PAD + hoA * 2) * W_PAD + woA * 2) * C_IN + sq * 16;
        int spB = sp_blk + 64 + srow;
        int nB  = spB / (H_OUT * W_OUT);
        int rmB = spB - nB * (H_OUT * W_OUT);
        int hoB = rmB / W_OUT;
        int woB = rmB - hoB * W_OUT;
        ga1 = xpad + ((size_t)(nB * H_PAD + hoB * 2) * W_PAD + woB * 2) * C_IN + sq * 16;
    }

    // ---- output mapping: wave tile 64co x 64sp (2x2 wave grid) ----
    const int cw = (wave >> 1) * 64;
    const int sw = (wave & 1) * 64;
    int out_base[4];
    #pragma unroll
    for (int jj = 0; jj < 4; ++jj) {
        int sp = sp_blk + sw + jj * 16 + s;
        int n  = sp / (H_OUT * W_OUT);
        int rm = sp - n * (H_OUT * W_OUT);
        int ho = rm / W_OUT;
        int wo = rm - ho * W_OUT;
        out_base[jj] = n * (C_OUT * H_OUT * W_OUT) + ho * W_OUT + wo;
    }

    v4i acc[4][4];
    #pragma unroll
    for (int i = 0; i < 4; ++i)
        #pragma unroll
        for (int jj = 0; jj < 4; ++jj)
            acc[i][jj] = (v4i){0, 0, 0, 0};

    // stage hk (tap = hk>>2, k-slice sl = hk&3) into buffer lb
    auto stage = [&](int hk, int8_t* lb) {
        const int tap = hk >> 2, sl = hk & 3;
        const int wo_ = tap * (C_OUT * C_IN) + sl * 64;
        const int ao_ = ((tap / 3) * W_PAD + (tap % 3)) * C_IN + sl * 64;
        glds16(gw0 + wo_, lb + t * 16);               // W rows 0..63
        glds16(gw1 + wo_, lb + 4096 + t * 16);        // W rows 64..127
        glds16(ga0 + ao_, lb + 8192 + t * 16);        // Act rows 0..63
        glds16(ga1 + ao_, lb + 12288 + t * 16);       // Act rows 64..127
    };

    // compute one stage (K=64) from buffer lb: 8 ds_read_b128, 16 MFMA
    auto compute = [&](const int8_t* lb) {
        const int stoff = (q ^ ((s >> 1) & 3)) * 16;  // swizzled chunk
        v4i a[4], b[4];
        #pragma unroll
        for (int i = 0; i < 4; ++i)
            a[i] = *(const v4i*)(lb + (cw + i * 16 + s) * 64 + stoff);
        #pragma unroll
        for (int jj = 0; jj < 4; ++jj)
            b[jj] = *(const v4i*)(lb + 8192 + (sw + jj * 16 + s) * 64 + stoff);
        #pragma unroll
        for (int i = 0; i < 4; ++i)
            #pragma unroll
            for (int jj = 0; jj < 4; ++jj)
                acc[i][jj] = __builtin_amdgcn_mfma_i32_16x16x64_i8(
                    a[i], b[jj], acc[i][jj], 0, 0, 0);
    };

    // ---- K loop: 36 stages, depth-2 counted-vmcnt, ONE barrier/stage ----
    stage(0, lds);
    stage(1, lds + 16384);
    #pragma unroll
    for (int hk = 0; hk < 36; ++hk) {
        // wait for stage hk's 4 loads (outstanding: hk, hk+1 -> 8 loads)
        if (hk < 35)
            asm volatile("s_waitcnt vmcnt(4)\n\ts_barrier" ::: "memory");
        else
            asm volatile("s_waitcnt vmcnt(0)\n\ts_barrier" ::: "memory");
        // barrier proves all waves retired buf((hk-1)%3) reads -> refill it
        if (hk + 2 < 36) stage(hk + 2, lds + ((hk + 2) % 3) * 16384);
        compute(lds + (hk % 3) * 16384);
    }

    // ---- epilogue: coalesced dword stores (lanes 0-15 = consecutive sp) ----
    #pragma unroll
    for (int jj = 0; jj < 4; ++jj) {
        #pragma unroll
        for (int i = 0; i < 4; ++i) {
            const int co0 = co_blk + cw + i * 16 + q * 4;
            #pragma unroll
            for (int r = 0; r < 4; ++r) {
                out[(size_t)out_base[jj] + (size_t)(co0 + r) * (H_OUT * W_OUT)] =
                    (float)acc[i][jj][r] * 0.0005f;
            }
        }
    }
}

// ---------------------------------------------------------------------------
// FINAL configuration (R4 winner restored, probe multiplicity removed).
// Budget (measured via R5/R6 probes): fills+overhead ~138us fixed,
// quant 25.0us (~88% of BW floor), conv 21.4us (~2x overlap-perfect floor,
// resistant to 4 structural variants). Remaining slack ~10us (<6%), below
// reliable EV per round -> roofline on confirmation.
// ---------------------------------------------------------------------------
extern "C" void kernel_launch(void* const* d_in, const int* in_sizes, int n_in,
                              void* d_out, int out_size, void* d_ws, size_t ws_size,
                              hipStream_t stream) {
    const float* x = (const float*)d_in[0];
    const float* w = (const float*)d_in[1];
    float* out = (float*)d_out;
    int8_t* xpad = (int8_t*)d_ws;
    int8_t* wqb  = xpad + XPAD_BYTES;

    quant_kernel<<<dim3(H_PAD, N_IMG + 10), 256, 0, stream>>>(x, xpad, w, wqb);
    conv_kernel<<<dim3(392), 256, 0, stream>>>(xpad, wqb, out);
}